// Round 3
// baseline (2108.534 us; speedup 1.0000x reference)
//
#include <hip/hip_runtime.h>
#include <hip/hip_bf16.h>
#include <hip/hip_fp16.h>

#define SEQ   320
#define GATES 1600
#define NCOL  3200
#define GDW   5     // workgroups per direction in the recurrent kernel
#define RPW   80    // h-rows owned per workgroup (400/5)
#define EXS   48    // exchange block stride in dwords (40 used, line-aligned)

typedef _Float16 half2v __attribute__((ext_vector_type(2)));
typedef _Float16 f16x8  __attribute__((ext_vector_type(8)));
typedef float    f32x4  __attribute__((ext_vector_type(4)));
union H2U { unsigned u; half2v h; __half2 hh; };

// ---------------------------------------------------------------- prep: embed->f16, bias sums, cvt W_ih_l0
__global__ __launch_bounds__(256) void prep_kernel(
    const int* __restrict__ words, const int* __restrict__ tags,
    const float* __restrict__ wemb, const float* __restrict__ temb,
    _Float16* __restrict__ Ah0,
    const float* __restrict__ bihl0,  const float* __restrict__ bhhl0,
    const float* __restrict__ bihl0r, const float* __restrict__ bhhl0r,
    const float* __restrict__ bihl1,  const float* __restrict__ bhhl1,
    const float* __restrict__ bihl1r, const float* __restrict__ bhhl1r,
    const float* __restrict__ mlpb1,
    float* __restrict__ bL0, float* __restrict__ bL1, float* __restrict__ bAB,
    const float* __restrict__ wih0, const float* __restrict__ wih0r,
    _Float16* __restrict__ BhA)
{
    const int b = blockIdx.x, t = threadIdx.x;
    if (b < 520) {                       // embeddings -> Ah0 (320 x 416, zero-pad)
        int i = b * 256 + t;
        if (i >= SEQ * 416) return;
        int tt = i / 416, c = i % 416;
        float v = 0.f;
        if (c < 300)      v = wemb[(size_t)words[tt] * 300 + c];
        else if (c < 400) v = temb[(size_t)tags[tt] * 100 + (c - 300)];
        Ah0[i] = (_Float16)v;
    } else if (b < 533) {                // bias sums
        int g = (b - 520) * 256 + t;
        if (g >= NCOL) return;
        if (g < GATES) {
            bL0[g] = bihl0[g] + bhhl0[g];
            bL1[g] = bihl1[g] + bhhl1[g];
            bAB[g] = mlpb1[g];
        } else {
            int q = g - GATES;
            bL0[g] = bihl0r[q] + bhhl0r[q];
            bL1[g] = bihl1r[q] + bhhl1r[q];
            bAB[g] = 0.f;
        }
    } else {                             // W_ih_l0 -> fp16 (3200 x 416, zero-pad K)
        int i = (b - 533) * 256 + t;
        if (i >= NCOL * 416) return;
        int n = i / 416, k = i % 416;
        float v = 0.f;
        if (k < 400)
            v = (n < GATES) ? wih0[(size_t)n * 400 + k]
                            : wih0r[(size_t)(n - GATES) * 400 + k];
        BhA[i] = (_Float16)v;
    }
}

// ---------------------------------------------------------------- cvt W_ih_l1 -> BhB, mlp_w1 -> BhA
__global__ __launch_bounds__(256) void cvt2_kernel(
    const float* __restrict__ wih1, const float* __restrict__ wih1r,
    _Float16* __restrict__ BhB,
    const float* __restrict__ mlpw1, _Float16* __restrict__ BhA)
{
    const int b = blockIdx.x, t = threadIdx.x;
    if (b < 10000) {
        int i = b * 256 + t;
        if (i >= NCOL * 800) return;
        int n = i / 800, k = i % 800;
        BhB[i] = (_Float16)((n < GATES) ? wih1[(size_t)n * 800 + k]
                                        : wih1r[(size_t)(n - GATES) * 800 + k]);
    } else {
        int i = (b - 10000) * 256 + t;
        if (i >= NCOL * 800) return;
        int n = i / 800, k = i % 800;
        BhA[i] = (_Float16)((n < GATES) ? mlpw1[(size_t)n * 1600 + k]
                                        : mlpw1[(size_t)(n - GATES) * 1600 + 800 + k]);
    }
}

// ---------------------------------------------------------------- MFMA f16 GEMM (as R6, verified)
__global__ __launch_bounds__(256) void gemm_f16(
    const _Float16* __restrict__ A, int Kp,
    const _Float16* __restrict__ B,
    const float* __restrict__ bias, float* __restrict__ C)
{
    const int tid  = threadIdx.x;
    const int w    = tid >> 6, lane = tid & 63;
    const int quad = lane >> 4, l16 = lane & 15;
    const int mb   = blockIdx.y * 32 + (w & 1) * 16;
    const int n0   = blockIdx.x * 64 + (w >> 1) * 32;
    const _Float16* Arow = A + (size_t)(mb + l16) * Kp + quad * 8;
    const _Float16* B0r  = B + (size_t)(n0 + l16) * Kp + quad * 8;
    const _Float16* B1r  = B0r + (size_t)16 * Kp;
    f32x4 acc0 = {0.f, 0.f, 0.f, 0.f}, acc1 = {0.f, 0.f, 0.f, 0.f};
#pragma unroll 4
    for (int k0 = 0; k0 < Kp; k0 += 32) {
        f16x8 a  = *(const f16x8*)(Arow + k0);
        f16x8 b0 = *(const f16x8*)(B0r + k0);
        f16x8 b1 = *(const f16x8*)(B1r + k0);
        acc0 = __builtin_amdgcn_mfma_f32_16x16x32_f16(a, b0, acc0, 0, 0, 0);
        acc1 = __builtin_amdgcn_mfma_f32_16x16x32_f16(a, b1, acc1, 0, 0, 0);
    }
    const int mr = mb + quad * 4;
    float bn0 = bias[n0 + l16], bn1 = bias[n0 + 16 + l16];
#pragma unroll
    for (int r = 0; r < 4; ++r) {
        C[(size_t)(mr + r) * NCOL + n0 + l16]      = acc0[r] + bn0;
        C[(size_t)(mr + r) * NCOL + n0 + 16 + l16] = acc1[r] + bn1;
    }
}

// ---------------------------------------------------------------- recurrence
// R10 = R9 with the workspace overlap fixed (R9's Ah2 clobbered BhA).
// Exchange-latency attack: 5 WGs/dir x 640 threads, 80 rows/WG.
// Thread role: rp=tid>>4 (row-pair), g=(tid>>2)&3 (gate), ks=tid&3
// (K-slice of 100 halves). 100 weight dwords/thread stay in VGPRs
// (launch_bounds(640,3) caps VGPR at 170 so all 10 waves are resident).
// Exchange: u64 packed stores (20 msgs/WG/step by lanes 0/32 of each wave)
// + u64 spin polls (80 pollers: 4 remote producers x 20) -> ~7x fewer
// atomic streams per producer line than R8, 4 remote producers vs 24.
// Barrier: raw s_waitcnt lgkmcnt(0) + s_barrier (NOT __syncthreads) so the
// exchange-store ACK (full MALL round trip) is never serialized into the
// step chain. h_prev LDS double-buffered, 4 slices x 52 dwords (50 used,
// 16B-aligned for b128 reads; 16 lanes/slice broadcast -> conflict-free).
// Sentinel = 0xFFFFFFFF per dword (|h|<1 so fp16 pair never all-ones);
// u64 store is atomic, both halves arrive together.
__global__ __launch_bounds__(640, 3) void lstm_layer(
    const float* __restrict__ gates,   // SEQ x 3200 (x@W_ih^T + biases)
    const float* __restrict__ whh_f, const float* __restrict__ whh_b,
    const float* __restrict__ h0f, const float* __restrict__ h0b,
    const float* __restrict__ c0f, const float* __restrict__ c0b,
    unsigned* __restrict__ ex,         // exchange region (re-sentineled per layer)
    _Float16* __restrict__ ah)         // SEQ x 800 fp16 h (input to next GEMM)
{
    __shared__ __align__(16) unsigned hbuf[2][208];  // 4 slices x 52 dwords, dbuf
    const int tid = threadIdx.x;
    const int dir = blockIdx.x >= GDW;
    const int wg  = blockIdx.x - dir * GDW;
    const float* whh = dir ? whh_b : whh_f;
    const float* h0d = dir ? h0b : h0f;
    const float* c0d = dir ? c0b : c0f;

    const int rp = tid >> 4;           // row-pair 0..39 -> rows {2rp, 2rp+1}
    const int g  = (tid >> 2) & 3;     // gate
    const int ks = tid & 3;            // k-slice (100 halves = 50 dwords)
    const int jA = wg * RPW + 2 * rp;  // first owned row (within direction)

    // persistent fp16 weights: 2 rows x 100 halves, packed 50 dwords each
    unsigned wrA[50], wrB[50];
    {
        const float2* wA = (const float2*)(whh + ((size_t)g * 400 + jA) * 400 + 100 * ks);
        const float2* wB = (const float2*)(whh + ((size_t)g * 400 + jA + 1) * 400 + 100 * ks);
#pragma unroll
        for (int i = 0; i < 50; ++i) {
            float2 fa = wA[i], fb = wB[i];
            H2U ca, cbu;
            ca.hh  = __floats2half2_rn(fa.x, fa.y);
            cbu.hh = __floats2half2_rn(fb.x, fb.y);
            wrA[i] = ca.u; wrB[i] = cbu.u;
        }
    }

    // poll constants (80 pollers: 4 remote producers x 20 u64 each)
    int pollq0 = 0, pollq1 = 0;
    const unsigned long long* pbase = nullptr;
    if (tid < 80) {
        int pp = tid / 20; pp += (pp >= wg);
        int u  = tid % 20;
        int q0 = pp * 40 + 2 * u;
        pollq0 = (q0 / 50) * 52 + q0 % 50;
        pollq1 = ((q0 + 1) / 50) * 52 + (q0 + 1) % 50;
        pbase  = (const unsigned long long*)(ex + ((size_t)(dir * GDW + pp) * SEQ) * EXS + 2 * u);
    }

    // own-store constants (lanes 0/32 of each wave store 2 packed row-pairs)
    const int w64  = tid >> 6;                 // wave 0..9
    const int hsel = (tid >> 5) & 1;           // half-wave select
    const int qo   = wg * 40 + 4 * w64 + 2 * hsel;
    const int own0 = (qo / 50) * 52 + qo % 50;
    const int own1 = ((qo + 1) / 50) * 52 + (qo + 1) % 50;
    unsigned long long* exo = (unsigned long long*)(ex + ((size_t)(dir * GDW + wg) * SEQ) * EXS
                                                    + 4 * w64 + 2 * hsel);
    unsigned* ahd = (unsigned*)ah;
    const int ahoff = dir * 200 + wg * 40 + 4 * w64 + 2 * hsel;
    const float* gbase = gates + dir * GATES + g * 400 + jA;
    float cA = c0d[jA], cB = c0d[jA + 1];

    for (int s = 0; s < SEQ; ++s) {
        const int row = dir ? (SEQ - 1 - s) : s;
        const int cb  = s & 1;
        // gate prefetch (independent of h_prev, overlaps the poll)
        float2 gv = *(const float2*)(gbase + (size_t)row * NCOL);

        if (s == 0) {
            if (tid < 100) {
                float4 f = ((const float4*)h0d)[tid];
                H2U a, b;
                a.hh = __floats2half2_rn(f.x, f.y);
                b.hh = __floats2half2_rn(f.z, f.w);
                int q0 = 2 * tid, q1 = 2 * tid + 1;
                hbuf[0][(q0 / 50) * 52 + q0 % 50] = a.u;
                hbuf[0][(q1 / 50) * 52 + q1 % 50] = b.u;
            }
        } else if (tid < 80) {
            const int rprev = dir ? row + 1 : row - 1;
            const unsigned long long* src = pbase + (size_t)rprev * (EXS / 2);
            unsigned long long v;
            do {
                v = __hip_atomic_load(src, __ATOMIC_RELAXED, __HIP_MEMORY_SCOPE_AGENT);
            } while (((unsigned)v == 0xFFFFFFFFu) || ((unsigned)(v >> 32) == 0xFFFFFFFFu));
            hbuf[cb][pollq0] = (unsigned)v;
            hbuf[cb][pollq1] = (unsigned)(v >> 32);
        }
        // LDS-only barrier: do NOT drain vmcnt (exchange-store ACK stays async)
        asm volatile("s_waitcnt lgkmcnt(0)" ::: "memory");
        __builtin_amdgcn_s_barrier();
        __builtin_amdgcn_sched_barrier(0);

        // dot: 50 dwords (12x b128 + 1x b64), reused for both rows
        const unsigned* hb = &hbuf[cb][ks * 52];
        float accA = 0.f, accB = 0.f;
#pragma unroll
        for (int i = 0; i < 12; ++i) {
            uint4 hq = *(const uint4*)(hb + 4 * i);
            H2U x0, x1, x2, x3, wa, wb;
            x0.u = hq.x; x1.u = hq.y; x2.u = hq.z; x3.u = hq.w;
            wa.u = wrA[4*i+0]; wb.u = wrB[4*i+0];
            accA = __builtin_amdgcn_fdot2(wa.h, x0.h, accA, false);
            accB = __builtin_amdgcn_fdot2(wb.h, x0.h, accB, false);
            wa.u = wrA[4*i+1]; wb.u = wrB[4*i+1];
            accA = __builtin_amdgcn_fdot2(wa.h, x1.h, accA, false);
            accB = __builtin_amdgcn_fdot2(wb.h, x1.h, accB, false);
            wa.u = wrA[4*i+2]; wb.u = wrB[4*i+2];
            accA = __builtin_amdgcn_fdot2(wa.h, x2.h, accA, false);
            accB = __builtin_amdgcn_fdot2(wb.h, x2.h, accB, false);
            wa.u = wrA[4*i+3]; wb.u = wrB[4*i+3];
            accA = __builtin_amdgcn_fdot2(wa.h, x3.h, accA, false);
            accB = __builtin_amdgcn_fdot2(wb.h, x3.h, accB, false);
        }
        {
            uint2 ht = *(const uint2*)(hb + 48);
            H2U x0, x1, wa, wb;
            x0.u = ht.x; x1.u = ht.y;
            wa.u = wrA[48]; wb.u = wrB[48];
            accA = __builtin_amdgcn_fdot2(wa.h, x0.h, accA, false);
            accB = __builtin_amdgcn_fdot2(wb.h, x0.h, accB, false);
            wa.u = wrA[49]; wb.u = wrB[49];
            accA = __builtin_amdgcn_fdot2(wa.h, x1.h, accA, false);
            accB = __builtin_amdgcn_fdot2(wb.h, x1.h, accB, false);
        }

        // ks-reduce (4 lanes) then add gate input
        accA += __shfl_xor(accA, 1); accA += __shfl_xor(accA, 2);
        accB += __shfl_xor(accB, 1); accB += __shfl_xor(accB, 2);
        accA += gv.x; accB += gv.y;

        // gate gather: value of gate g^t sits at xor-distance t*4
        float a1 = __shfl_xor(accA, 4), a2 = __shfl_xor(accA, 8), a3 = __shfl_xor(accA, 12);
        float b1 = __shfl_xor(accB, 4), b2 = __shfl_xor(accB, 8), b3 = __shfl_xor(accB, 12);
        float giA = g==0?accA : g==1?a1 : g==2?a2 : a3;
        float gfA = g==1?accA : g==0?a1 : g==3?a2 : a3;
        float ggA = g==2?accA : g==3?a1 : g==0?a2 : a3;
        float goA = g==3?accA : g==2?a1 : g==1?a2 : a3;
        float giB = g==0?accB : g==1?b1 : g==2?b2 : b3;
        float gfB = g==1?accB : g==0?b1 : g==3?b2 : b3;
        float ggB = g==2?accB : g==3?b1 : g==0?b2 : b3;
        float goB = g==3?accB : g==2?b1 : g==1?b2 : b3;

        // activations (redundant in all 16 lanes of the row-pair; consistent)
        float ivA = 1.f / (1.f + __expf(-giA)), fvA = 1.f / (1.f + __expf(-gfA));
        float ovA = 1.f / (1.f + __expf(-goA)), tgA = 1.f - 2.f / (1.f + __expf(2.f * ggA));
        float ivB = 1.f / (1.f + __expf(-giB)), fvB = 1.f / (1.f + __expf(-gfB));
        float ovB = 1.f / (1.f + __expf(-goB)), tgB = 1.f - 2.f / (1.f + __expf(2.f * ggB));
        cA = fvA * cA + ivA * tgA;
        cB = fvB * cB + ivB * tgB;
        float hA = ovA * (1.f - 2.f / (1.f + __expf(2.f * cA)));
        float hB = ovB * (1.f - 2.f / (1.f + __expf(2.f * cB)));

        // pack pair -> dword; lanes 0/32 of each wave assemble u64 (2 pairs)
        H2U pk; pk.hh = __floats2half2_rn(hA, hB);
        unsigned hi = __shfl_xor(pk.u, 16);
        if ((tid & 31) == 0) {
            unsigned long long val = ((unsigned long long)hi << 32) | pk.u;
            __hip_atomic_store(exo + (size_t)row * (EXS / 2), val,
                               __ATOMIC_RELAXED, __HIP_MEMORY_SCOPE_AGENT);
            *(uint2*)(ahd + (size_t)row * 400 + ahoff) = make_uint2(pk.u, hi);
            hbuf[cb ^ 1][own0] = pk.u;
            hbuf[cb ^ 1][own1] = hi;
        }
        // hazards: pollers(s)+init write hbuf[cb] pre-barrier(s), read after;
        // own-writes(s) go to hbuf[cb^1], read at s+1 after barrier(s+1);
        // pollers(s+1) write hbuf[cb^1] remote slots (disjoint from own slots).
        // next write to hbuf[cb] is at s+1 (own) / s+2 (pollers), both after
        // barrier(s+1) in program order, which follows all step-s reads. safe.
    }
}

// ---------------------------------------------------------------- fused scorer (+ border rows)
__global__ __launch_bounds__(256) void scores_kernel(
    const float* __restrict__ ab, const float* __restrict__ w2,
    const float* __restrict__ b2, float* __restrict__ out)
{
    if (blockIdx.y == 20) {              // border: row 0 / col 0
        int i = blockIdx.x * 256 + threadIdx.y * 16 + threadIdx.x;
        if (blockIdx.x < 2 && i < 321) {
            out[i]               = (i == 0) ? 1.f : 0.f;
            out[(size_t)i * 321] = (i == 0) ? 1.f : 0.f;
        }
        return;
    }
    __shared__ float a_s[16 * 132];
    __shared__ float b_s[16 * 132];
    __shared__ float w_s[128];
    const int tx = threadIdx.x, ty = threadIdx.y;
    const int tid = ty * 16 + tx;
    const int n0 = blockIdx.y * 16, d0 = blockIdx.x * 16;
    float acc = 0.f;
    for (int kc = 0; kc < 1600; kc += 128) {
        for (int i = tid; i < 16 * 128; i += 256) {
            int r = i >> 7, c = i & 127;
            a_s[r * 132 + c] = ab[(size_t)(n0 + r) * NCOL + kc + c];
            b_s[r * 132 + c] = ab[(size_t)(d0 + r) * NCOL + 1600 + kc + c];
        }
        if (tid < 128) w_s[tid] = w2[kc + tid];
        __syncthreads();
#pragma unroll
        for (int k = 0; k < 128; k += 4) {
            float4 av = *(const float4*)&a_s[ty * 132 + k];
            float4 bv = *(const float4*)&b_s[tx * 132 + k];
            float4 wv = *(const float4*)&w_s[k];
            acc += fmaxf(av.x + bv.x, 0.f) * wv.x;
            acc += fmaxf(av.y + bv.y, 0.f) * wv.y;
            acc += fmaxf(av.z + bv.z, 0.f) * wv.z;
            acc += fmaxf(av.w + bv.w, 0.f) * wv.w;
        }
        __syncthreads();
    }
    int n = n0 + ty, d = d0 + tx;
    out[(size_t)(n + 1) * 321 + (d + 1)] = (n == d) ? 0.f : (acc + b2[0]);
}

// ---------------------------------------------------------------- launcher
extern "C" void kernel_launch(void* const* d_in, const int* in_sizes, int n_in,
                              void* d_out, int out_size, void* d_ws, size_t ws_size,
                              hipStream_t stream)
{
    const int*   words    = (const int*)d_in[0];
    const int*   tags     = (const int*)d_in[1];
    const float* wemb     = (const float*)d_in[3];
    const float* temb     = (const float*)d_in[4];
    const float* h0       = (const float*)d_in[5];
    const float* c0       = (const float*)d_in[6];
    const float* w_ih_l0  = (const float*)d_in[7];
    const float* w_hh_l0  = (const float*)d_in[8];
    const float* b_ih_l0  = (const float*)d_in[9];
    const float* b_hh_l0  = (const float*)d_in[10];
    const float* w_ih_l0r = (const float*)d_in[11];
    const float* w_hh_l0r = (const float*)d_in[12];
    const float* b_ih_l0r = (const float*)d_in[13];
    const float* b_hh_l0r = (const float*)d_in[14];
    const float* w_ih_l1  = (const float*)d_in[15];
    const float* w_hh_l1  = (const float*)d_in[16];
    const float* b_ih_l1  = (const float*)d_in[17];
    const float* b_hh_l1  = (const float*)d_in[18];
    const float* w_ih_l1r = (const float*)d_in[19];
    const float* w_hh_l1r = (const float*)d_in[20];
    const float* b_ih_l1r = (const float*)d_in[21];
    const float* b_hh_l1r = (const float*)d_in[22];
    const float* mlp_w1   = (const float*)d_in[23];
    const float* mlp_b1   = (const float*)d_in[24];
    const float* mlp_w2   = (const float*)d_in[25];
    const float* mlp_b2   = (const float*)d_in[26];
    float* out = (float*)d_out;

    // workspace map (f32 offsets) — verified non-overlapping:
    //   gates   0         .. 1,024,000   (320*3200)
    //   biasL0  1,024,000 .. 1,027,200
    //   biasL1  1,027,200 .. 1,030,400
    //   biasAB  1,030,400 .. 1,033,600
    //   ex      1,033,600 .. 1,187,200   (2*5*320*48 u32)
    //   Ah0     1,187,200 .. 1,253,760   (320*416 f16 = 66,560 f32)
    //   Ah1     1,253,760 .. 1,381,760   (320*800 f16 = 128,000 f32)
    //   Ah2     1,381,760 .. 1,509,760   (320*800 f16)
    //   BhA     1,509,760 .. 2,789,760   (3200*800 f16 = 1,280,000 f32)
    //   BhB     2,789,760 .. 4,069,760   (3200*800 f16)
    float* ws      = (float*)d_ws;
    float*    gates  = ws;
    float*    biasL0 = ws + 1024000;
    float*    biasL1 = ws + 1027200;
    float*    biasAB = ws + 1030400;
    unsigned* ex     = (unsigned*)(ws + 1033600);
    _Float16* Ah0    = (_Float16*)(ws + 1187200);
    _Float16* Ah1    = (_Float16*)(ws + 1253760);
    _Float16* Ah2    = (_Float16*)(ws + 1381760);
    _Float16* BhA    = (_Float16*)(ws + 1509760);
    _Float16* BhB    = (_Float16*)(ws + 2789760);

    // sentinel-fill the exchange region (data doubles as ready flag)
    hipMemsetAsync(ex, 0xFF, 153600u * 4, stream);

    prep_kernel<<<5733, 256, 0, stream>>>(
        words, tags, wemb, temb, Ah0,
        b_ih_l0, b_hh_l0, b_ih_l0r, b_hh_l0r,
        b_ih_l1, b_hh_l1, b_ih_l1r, b_hh_l1r,
        mlp_b1, biasL0, biasL1, biasAB, w_ih_l0, w_ih_l0r, BhA);

    gemm_f16<<<dim3(50, 10), 256, 0, stream>>>(Ah0, 416, BhA, biasL0, gates);
    cvt2_kernel<<<20000, 256, 0, stream>>>(w_ih_l1, w_ih_l1r, BhB, mlp_w1, BhA);
    lstm_layer<<<2 * GDW, 640, 0, stream>>>(gates, w_hh_l0, w_hh_l0r,
                                            h0, h0 + 400, c0, c0 + 400, ex, Ah1);
    // re-sentinel for layer 1 (stream-ordered after lstm L0)
    hipMemsetAsync(ex, 0xFF, 153600u * 4, stream);
    gemm_f16<<<dim3(50, 10), 256, 0, stream>>>(Ah1, 800, BhB, biasL1, gates);
    lstm_layer<<<2 * GDW, 640, 0, stream>>>(gates, w_hh_l1, w_hh_l1r,
                                            h0 + 800, h0 + 1200, c0 + 800, c0 + 1200,
                                            ex, Ah2);
    gemm_f16<<<dim3(50, 10), 256, 0, stream>>>(Ah2, 800, BhA, biasAB, gates);

    scores_kernel<<<dim3(20, 21), dim3(16, 16), 0, stream>>>(gates, mlp_w2, mlp_b2, out);
}

// Round 4
// 1372.900 us; speedup vs baseline: 1.5358x; 1.5358x over previous
//
#include <hip/hip_runtime.h>
#include <hip/hip_bf16.h>
#include <hip/hip_fp16.h>

#define SEQ   320
#define GATES 1600
#define NCOL  3200
#define GDW   16    // workgroups per direction in the recurrent kernel
#define RPW   25    // h-rows owned per workgroup (400/16)

typedef _Float16 half2v __attribute__((ext_vector_type(2)));
typedef _Float16 f16x8  __attribute__((ext_vector_type(8)));
typedef float    f32x4  __attribute__((ext_vector_type(4)));
union H2U { unsigned u; half2v h; __half2 hh; };

// ---------------------------------------------------------------- prep: embed->f16, bias sums, cvt W_ih_l0
__global__ __launch_bounds__(256) void prep_kernel(
    const int* __restrict__ words, const int* __restrict__ tags,
    const float* __restrict__ wemb, const float* __restrict__ temb,
    _Float16* __restrict__ Ah0,
    const float* __restrict__ bihl0,  const float* __restrict__ bhhl0,
    const float* __restrict__ bihl0r, const float* __restrict__ bhhl0r,
    const float* __restrict__ bihl1,  const float* __restrict__ bhhl1,
    const float* __restrict__ bihl1r, const float* __restrict__ bhhl1r,
    const float* __restrict__ mlpb1,
    float* __restrict__ bL0, float* __restrict__ bL1, float* __restrict__ bAB,
    const float* __restrict__ wih0, const float* __restrict__ wih0r,
    _Float16* __restrict__ BhA)
{
    const int b = blockIdx.x, t = threadIdx.x;
    if (b < 520) {                       // embeddings -> Ah0 (320 x 416, zero-pad)
        int i = b * 256 + t;
        if (i >= SEQ * 416) return;
        int tt = i / 416, c = i % 416;
        float v = 0.f;
        if (c < 300)      v = wemb[(size_t)words[tt] * 300 + c];
        else if (c < 400) v = temb[(size_t)tags[tt] * 100 + (c - 300)];
        Ah0[i] = (_Float16)v;
    } else if (b < 533) {                // bias sums
        int g = (b - 520) * 256 + t;
        if (g >= NCOL) return;
        if (g < GATES) {
            bL0[g] = bihl0[g] + bhhl0[g];
            bL1[g] = bihl1[g] + bhhl1[g];
            bAB[g] = mlpb1[g];
        } else {
            int q = g - GATES;
            bL0[g] = bihl0r[q] + bhhl0r[q];
            bL1[g] = bihl1r[q] + bhhl1r[q];
            bAB[g] = 0.f;
        }
    } else {                             // W_ih_l0 -> fp16 (3200 x 416, zero-pad K)
        int i = (b - 533) * 256 + t;
        if (i >= NCOL * 416) return;
        int n = i / 416, k = i % 416;
        float v = 0.f;
        if (k < 400)
            v = (n < GATES) ? wih0[(size_t)n * 400 + k]
                            : wih0r[(size_t)(n - GATES) * 400 + k];
        BhA[i] = (_Float16)v;
    }
}

// ---------------------------------------------------------------- cvt W_ih_l1 -> BhB, mlp_w1 -> BhA
__global__ __launch_bounds__(256) void cvt2_kernel(
    const float* __restrict__ wih1, const float* __restrict__ wih1r,
    _Float16* __restrict__ BhB,
    const float* __restrict__ mlpw1, _Float16* __restrict__ BhA)
{
    const int b = blockIdx.x, t = threadIdx.x;
    if (b < 10000) {
        int i = b * 256 + t;
        if (i >= NCOL * 800) return;
        int n = i / 800, k = i % 800;
        BhB[i] = (_Float16)((n < GATES) ? wih1[(size_t)n * 800 + k]
                                        : wih1r[(size_t)(n - GATES) * 800 + k]);
    } else {
        int i = (b - 10000) * 256 + t;
        if (i >= NCOL * 800) return;
        int n = i / 800, k = i % 800;
        BhA[i] = (_Float16)((n < GATES) ? mlpw1[(size_t)n * 1600 + k]
                                        : mlpw1[(size_t)(n - GATES) * 1600 + 800 + k]);
    }
}

// ---------------------------------------------------------------- MFMA f16 GEMM (as R6, verified)
__global__ __launch_bounds__(256) void gemm_f16(
    const _Float16* __restrict__ A, int Kp,
    const _Float16* __restrict__ B,
    const float* __restrict__ bias, float* __restrict__ C)
{
    const int tid  = threadIdx.x;
    const int w    = tid >> 6, lane = tid & 63;
    const int quad = lane >> 4, l16 = lane & 15;
    const int mb   = blockIdx.y * 32 + (w & 1) * 16;
    const int n0   = blockIdx.x * 64 + (w >> 1) * 32;
    const _Float16* Arow = A + (size_t)(mb + l16) * Kp + quad * 8;
    const _Float16* B0r  = B + (size_t)(n0 + l16) * Kp + quad * 8;
    const _Float16* B1r  = B0r + (size_t)16 * Kp;
    f32x4 acc0 = {0.f, 0.f, 0.f, 0.f}, acc1 = {0.f, 0.f, 0.f, 0.f};
#pragma unroll 4
    for (int k0 = 0; k0 < Kp; k0 += 32) {
        f16x8 a  = *(const f16x8*)(Arow + k0);
        f16x8 b0 = *(const f16x8*)(B0r + k0);
        f16x8 b1 = *(const f16x8*)(B1r + k0);
        acc0 = __builtin_amdgcn_mfma_f32_16x16x32_f16(a, b0, acc0, 0, 0, 0);
        acc1 = __builtin_amdgcn_mfma_f32_16x16x32_f16(a, b1, acc1, 0, 0, 0);
    }
    const int mr = mb + quad * 4;
    float bn0 = bias[n0 + l16], bn1 = bias[n0 + 16 + l16];
#pragma unroll
    for (int r = 0; r < 4; ++r) {
        C[(size_t)(mr + r) * NCOL + n0 + l16]      = acc0[r] + bn0;
        C[(size_t)(mr + r) * NCOL + n0 + 16 + l16] = acc1[r] + bn1;
    }
}

// ---------------------------------------------------------------- recurrence
// R11 = R7 (measured 558 us/dispatch) with exactly ONE change: both
// __syncthreads() replaced by {s_waitcnt lgkmcnt(0); s_barrier}. The
// default barrier's vmcnt(0) drain serialized the agent-scope exchange
// store ACK (full MALL round trip) into every step; LDS ordering only
// needs lgkmcnt. No intra-WG global communication exists (exchange is
// inter-WG, ah is read by the next kernel, gates are read-only), so
// dropping the vmcnt drain is semantically safe. Poll loads are ordered
// by data dependency (value consumed before LDS store of it).
__global__ __launch_bounds__(1024, 4) void lstm_layer(
    const float* __restrict__ gates,   // SEQ x 3200 (x@W_ih^T + biases)
    const float* __restrict__ whh_f, const float* __restrict__ whh_b,
    const float* __restrict__ h0f, const float* __restrict__ h0b,
    const float* __restrict__ c0f, const float* __restrict__ c0b,
    unsigned* __restrict__ ex,         // this layer's exchange region
    _Float16* __restrict__ ah)         // SEQ x 800 fp16 h (input to next GEMM)
{
    __shared__ unsigned h_pk[200];     // 400 halfs of h_prev
    __shared__ float part[16][28];
    unsigned short* hs = (unsigned short*)h_pk;
    const int tid = threadIdx.x;
    const int dir = blockIdx.x >> 4;
    const int wg  = blockIdx.x & 15;
    const int j0  = wg * RPW;
    const float* whh = dir ? whh_b : whh_f;
    const float* h0d = dir ? h0b : h0f;
    const float* c0d = dir ? c0b : c0f;

    const int w    = tid >> 6;         // wave 0..15
    const int lane = tid & 63;
    const int g    = w & 3;            // gate
    const int kq   = w >> 2;           // k-quarter (100 elems)
    const int half = lane & 1;         // k-split within quarter
    const int r    = lane >> 1;        // row within WG (active if r<25)
    const int jrow = j0 + (r < RPW ? r : RPW - 1);

    // one-time: 52 W_hh weights/thread, fp16-packed into 26 uints (spill-proof)
    unsigned wr[26];
    {
        const float2* wp = (const float2*)(whh + (size_t)(g * 400 + jrow) * 400 +
                                           kq * 100 + 48 * half);
#pragma unroll
        for (int i = 0; i < 26; ++i) {
            H2U cv; float2 f = wp[i];
            cv.hh = __floats2half2_rn(f.x, f.y);
            wr[i] = (half == 0 && i >= 24) ? 0u : cv.u;
        }
    }

    const int pp = tid / 13;           // producer block polled (tid<208)
    const int pd = tid - pp * 13;      // dword within block
    float c_prev = (tid < RPW) ? c0d[j0 + tid] : 0.f;

    for (int s = 0; s < 320; ++s) {
        const int row = dir ? (319 - s) : s;

        // gate prefetch (independent of h_prev, overlaps the poll)
        float gv0 = 0.f, gv1 = 0.f, gv2 = 0.f, gv3 = 0.f;
        if (tid < RPW) {
            const float* gx = gates + (size_t)row * NCOL + dir * GATES + j0 + tid;
            gv0 = gx[0]; gv1 = gx[400]; gv2 = gx[800]; gv3 = gx[1200];
        }

        if (s == 0) {
            if (tid < 100) {
                float4 f = ((const float4*)h0d)[tid];
                H2U a, b;
                a.hh = __floats2half2_rn(f.x, f.y);
                b.hh = __floats2half2_rn(f.z, f.w);
                ((uint2*)h_pk)[tid] = make_uint2(a.u, b.u);
            }
        } else if (tid < 208 && pp != wg) {
            const int rp = dir ? (row + 1) : (row - 1);
            const unsigned* src = ex + (((size_t)dir * GDW + pp) * SEQ + rp) * 16 + pd;
            unsigned v;
            for (;;) {
                v = __hip_atomic_load(src, __ATOMIC_RELAXED, __HIP_MEMORY_SCOPE_AGENT);
                if ((v & 0xFFFFu) != 0xFFFFu &&
                    (pd == 12 || (v >> 16) != 0xFFFFu)) break;
            }
            const int hb = pp * RPW + pd * 2;
            hs[hb] = (unsigned short)(v & 0xFFFFu);
            if (pd < 12) hs[hb + 1] = (unsigned short)(v >> 16);
        }
        // barrier 1: LDS-only drain (no vmcnt -> exchange/ah store ACKs and
        // gate-prefetch loads stay in flight across the barrier)
        asm volatile("s_waitcnt lgkmcnt(0)" ::: "memory");
        __builtin_amdgcn_s_barrier();

        // partial dot: 52 halves via 13 ds_read_b64 + 26 v_dot2_f32_f16
        {
            const uint2* hp2 = (const uint2*)h_pk + kq * 25 + 12 * half;
            float acc = 0.f;
#pragma unroll
            for (int i = 0; i < 13; ++i) {
                uint2 hv2 = hp2[i];
                H2U w0, w1, x0, x1;
                w0.u = wr[2 * i]; w1.u = wr[2 * i + 1];
                x0.u = hv2.x;     x1.u = hv2.y;
                acc = __builtin_amdgcn_fdot2(w0.h, x0.h, acc, false);
                acc = __builtin_amdgcn_fdot2(w1.h, x1.h, acc, false);
            }
            acc += __shfl_xor(acc, 1, 64);
            if (half == 0 && r < RPW) part[w][r] = acc;
        }
        // barrier 2: LDS-only drain
        asm volatile("s_waitcnt lgkmcnt(0)" ::: "memory");
        __builtin_amdgcn_s_barrier();

        // activation + exchange store (wave 0 only)
        float hv = 0.f;
        if (tid < RPW) {
            float gi = gv0 + ((part[0][tid] + part[4][tid]) + (part[8][tid]  + part[12][tid]));
            float gf = gv1 + ((part[1][tid] + part[5][tid]) + (part[9][tid]  + part[13][tid]));
            float gg = gv2 + ((part[2][tid] + part[6][tid]) + (part[10][tid] + part[14][tid]));
            float go = gv3 + ((part[3][tid] + part[7][tid]) + (part[11][tid] + part[15][tid]));
            float iv = 1.f / (1.f + __expf(-gi));
            float fv = 1.f / (1.f + __expf(-gf));
            float ov = 1.f / (1.f + __expf(-go));
            float tg = 1.f - 2.f / (1.f + __expf(2.f * gg));
            c_prev = fv * c_prev + iv * tg;
            float tc = 1.f - 2.f / (1.f + __expf(2.f * c_prev));
            hv = ov * tc;
        }
        if (w == 0) {
            int i0 = 2 * lane     < 63 ? 2 * lane     : 63;
            int i1 = 2 * lane + 1 < 63 ? 2 * lane + 1 : 63;
            float xlo = __shfl(hv, i0, 64);
            float xhi = __shfl(hv, i1, 64);
            if (lane < 13) {                 // one private 64B line per step
                H2U pk;
                pk.hh = __floats2half2_rn(xlo, (2 * lane + 1 < RPW) ? xhi : 0.f);
                __hip_atomic_store(ex + (((size_t)dir * GDW + wg) * SEQ + row) * 16 + lane,
                                   pk.u, __ATOMIC_RELAXED, __HIP_MEMORY_SCOPE_AGENT);
            }
            if (tid < RPW) {                 // fp16 h for next GEMM + own-row LDS
                ah[(size_t)row * 800 + dir * 400 + j0 + tid] = (_Float16)hv;
                H2U o; o.hh = __floats2half2_rn(hv, 0.f);
                hs[RPW * wg + tid] = (unsigned short)(o.u & 0xFFFFu);
            }
        }
        // hazards: h_pk written (pollers + act own-range) between barrier-2(s)
        // and barrier-1(s+1), read between barrier-1 and barrier-2; part[]
        // written pre-barrier-2, read post; disjoint LDS ranges. All writes
        // are ds ops, drained by lgkmcnt(0) before each s_barrier. safe.
    }
}

// ---------------------------------------------------------------- fused scorer (+ border rows)
__global__ __launch_bounds__(256) void scores_kernel(
    const float* __restrict__ ab, const float* __restrict__ w2,
    const float* __restrict__ b2, float* __restrict__ out)
{
    if (blockIdx.y == 20) {              // border: row 0 / col 0
        int i = blockIdx.x * 256 + threadIdx.y * 16 + threadIdx.x;
        if (blockIdx.x < 2 && i < 321) {
            out[i]               = (i == 0) ? 1.f : 0.f;
            out[(size_t)i * 321] = (i == 0) ? 1.f : 0.f;
        }
        return;
    }
    __shared__ float a_s[16 * 132];
    __shared__ float b_s[16 * 132];
    __shared__ float w_s[128];
    const int tx = threadIdx.x, ty = threadIdx.y;
    const int tid = ty * 16 + tx;
    const int n0 = blockIdx.y * 16, d0 = blockIdx.x * 16;
    float acc = 0.f;
    for (int kc = 0; kc < 1600; kc += 128) {
        for (int i = tid; i < 16 * 128; i += 256) {
            int r = i >> 7, c = i & 127;
            a_s[r * 132 + c] = ab[(size_t)(n0 + r) * NCOL + kc + c];
            b_s[r * 132 + c] = ab[(size_t)(d0 + r) * NCOL + 1600 + kc + c];
        }
        if (tid < 128) w_s[tid] = w2[kc + tid];
        __syncthreads();
#pragma unroll
        for (int k = 0; k < 128; k += 4) {
            float4 av = *(const float4*)&a_s[ty * 132 + k];
            float4 bv = *(const float4*)&b_s[tx * 132 + k];
            float4 wv = *(const float4*)&w_s[k];
            acc += fmaxf(av.x + bv.x, 0.f) * wv.x;
            acc += fmaxf(av.y + bv.y, 0.f) * wv.y;
            acc += fmaxf(av.z + bv.z, 0.f) * wv.z;
            acc += fmaxf(av.w + bv.w, 0.f) * wv.w;
        }
        __syncthreads();
    }
    int n = n0 + ty, d = d0 + tx;
    out[(size_t)(n + 1) * 321 + (d + 1)] = (n == d) ? 0.f : (acc + b2[0]);
}

// ---------------------------------------------------------------- launcher
extern "C" void kernel_launch(void* const* d_in, const int* in_sizes, int n_in,
                              void* d_out, int out_size, void* d_ws, size_t ws_size,
                              hipStream_t stream)
{
    const int*   words    = (const int*)d_in[0];
    const int*   tags     = (const int*)d_in[1];
    const float* wemb     = (const float*)d_in[3];
    const float* temb     = (const float*)d_in[4];
    const float* h0       = (const float*)d_in[5];
    const float* c0       = (const float*)d_in[6];
    const float* w_ih_l0  = (const float*)d_in[7];
    const float* w_hh_l0  = (const float*)d_in[8];
    const float* b_ih_l0  = (const float*)d_in[9];
    const float* b_hh_l0  = (const float*)d_in[10];
    const float* w_ih_l0r = (const float*)d_in[11];
    const float* w_hh_l0r = (const float*)d_in[12];
    const float* b_ih_l0r = (const float*)d_in[13];
    const float* b_hh_l0r = (const float*)d_in[14];
    const float* w_ih_l1  = (const float*)d_in[15];
    const float* w_hh_l1  = (const float*)d_in[16];
    const float* b_ih_l1  = (const float*)d_in[17];
    const float* b_hh_l1  = (const float*)d_in[18];
    const float* w_ih_l1r = (const float*)d_in[19];
    const float* w_hh_l1r = (const float*)d_in[20];
    const float* b_ih_l1r = (const float*)d_in[21];
    const float* b_hh_l1r = (const float*)d_in[22];
    const float* mlp_w1   = (const float*)d_in[23];
    const float* mlp_b1   = (const float*)d_in[24];
    const float* mlp_w2   = (const float*)d_in[25];
    const float* mlp_b2   = (const float*)d_in[26];
    float* out = (float*)d_out;

    float* ws      = (float*)d_ws;
    float*    gates  = ws;                              // 320*3200 = 1,024,000 f32
    float*    biasL0 = ws + 1024000;
    float*    biasL1 = ws + 1027200;
    float*    biasAB = ws + 1030400;
    unsigned* ex     = (unsigned*)(ws + 1033600);       // 2 layers x 163,840 uints
    _Float16* Ah0    = (_Float16*)(ws + 1361280);       // 320*416 halves
    _Float16* Ah1    = (_Float16*)(ws + 1427840);       // 320*800 halves
    _Float16* Ah2    = (_Float16*)(ws + 1555840);       // 320*800 halves
    _Float16* BhA    = (_Float16*)(ws + 1683840);       // up to 3200*800 halves
    _Float16* BhB    = (_Float16*)(ws + 2963840);       // 3200*800 halves
    unsigned* ex0 = ex, *ex1 = ex + 163840;

    // sentinel-fill the exchange blocks (data doubles as ready flag)
    hipMemsetAsync(ex, 0xFF, 327680u * 4, stream);

    prep_kernel<<<5733, 256, 0, stream>>>(
        words, tags, wemb, temb, Ah0,
        b_ih_l0, b_hh_l0, b_ih_l0r, b_hh_l0r,
        b_ih_l1, b_hh_l1, b_ih_l1r, b_hh_l1r,
        mlp_b1, biasL0, biasL1, biasAB, w_ih_l0, w_ih_l0r, BhA);

    gemm_f16<<<dim3(50, 10), 256, 0, stream>>>(Ah0, 416, BhA, biasL0, gates);
    cvt2_kernel<<<20000, 256, 0, stream>>>(w_ih_l1, w_ih_l1r, BhB, mlp_w1, BhA);
    lstm_layer<<<2 * GDW, 1024, 0, stream>>>(gates, w_hh_l0, w_hh_l0r,
                                             h0, h0 + 400, c0, c0 + 400, ex0, Ah1);
    gemm_f16<<<dim3(50, 10), 256, 0, stream>>>(Ah1, 800, BhB, biasL1, gates);
    lstm_layer<<<2 * GDW, 1024, 0, stream>>>(gates, w_hh_l1, w_hh_l1r,
                                             h0 + 800, h0 + 1200, c0 + 800, c0 + 1200,
                                             ex1, Ah2);
    gemm_f16<<<dim3(50, 10), 256, 0, stream>>>(Ah2, 800, BhA, biasAB, gates);

    scores_kernel<<<dim3(20, 21), dim3(16, 16), 0, stream>>>(gates, mlp_w2, mlp_b2, out);
}

// Round 5
// 1272.108 us; speedup vs baseline: 1.6575x; 1.0792x over previous
//
#include <hip/hip_runtime.h>
#include <hip/hip_bf16.h>
#include <hip/hip_fp16.h>

#define SEQ   320
#define GATES 1600
#define NCOL  3200
#define GDW   16    // workgroups per direction in the recurrent kernel
#define RPW   25    // h-rows owned per workgroup (400/16)
#define EXN   163840 // dwords per exchange plane (2*16*320*16)

typedef _Float16 half2v __attribute__((ext_vector_type(2)));
typedef _Float16 f16x8  __attribute__((ext_vector_type(8)));
typedef float    f32x4  __attribute__((ext_vector_type(4)));
union H2U { unsigned u; half2v h; __half2 hh; };

// ---------------------------------------------------------------- prep: embed->f16, bias sums, cvt W_ih_l0
__global__ __launch_bounds__(256) void prep_kernel(
    const int* __restrict__ words, const int* __restrict__ tags,
    const float* __restrict__ wemb, const float* __restrict__ temb,
    _Float16* __restrict__ Ah0,
    const float* __restrict__ bihl0,  const float* __restrict__ bhhl0,
    const float* __restrict__ bihl0r, const float* __restrict__ bhhl0r,
    const float* __restrict__ bihl1,  const float* __restrict__ bhhl1,
    const float* __restrict__ bihl1r, const float* __restrict__ bhhl1r,
    const float* __restrict__ mlpb1,
    float* __restrict__ bL0, float* __restrict__ bL1, float* __restrict__ bAB,
    const float* __restrict__ wih0, const float* __restrict__ wih0r,
    _Float16* __restrict__ BhA)
{
    const int b = blockIdx.x, t = threadIdx.x;
    if (b < 520) {                       // embeddings -> Ah0 (320 x 416, zero-pad)
        int i = b * 256 + t;
        if (i >= SEQ * 416) return;
        int tt = i / 416, c = i % 416;
        float v = 0.f;
        if (c < 300)      v = wemb[(size_t)words[tt] * 300 + c];
        else if (c < 400) v = temb[(size_t)tags[tt] * 100 + (c - 300)];
        Ah0[i] = (_Float16)v;
    } else if (b < 533) {                // bias sums
        int g = (b - 520) * 256 + t;
        if (g >= NCOL) return;
        if (g < GATES) {
            bL0[g] = bihl0[g] + bhhl0[g];
            bL1[g] = bihl1[g] + bhhl1[g];
            bAB[g] = mlpb1[g];
        } else {
            int q = g - GATES;
            bL0[g] = bihl0r[q] + bhhl0r[q];
            bL1[g] = bihl1r[q] + bhhl1r[q];
            bAB[g] = 0.f;
        }
    } else {                             // W_ih_l0 -> fp16 (3200 x 416, zero-pad K)
        int i = (b - 533) * 256 + t;
        if (i >= NCOL * 416) return;
        int n = i / 416, k = i % 416;
        float v = 0.f;
        if (k < 400)
            v = (n < GATES) ? wih0[(size_t)n * 400 + k]
                            : wih0r[(size_t)(n - GATES) * 400 + k];
        BhA[i] = (_Float16)v;
    }
}

// ---------------------------------------------------------------- cvt W_ih_l1 -> BhB, mlp_w1 -> BhA
__global__ __launch_bounds__(256) void cvt2_kernel(
    const float* __restrict__ wih1, const float* __restrict__ wih1r,
    _Float16* __restrict__ BhB,
    const float* __restrict__ mlpw1, _Float16* __restrict__ BhA)
{
    const int b = blockIdx.x, t = threadIdx.x;
    if (b < 10000) {
        int i = b * 256 + t;
        if (i >= NCOL * 800) return;
        int n = i / 800, k = i % 800;
        BhB[i] = (_Float16)((n < GATES) ? wih1[(size_t)n * 800 + k]
                                        : wih1r[(size_t)(n - GATES) * 800 + k]);
    } else {
        int i = (b - 10000) * 256 + t;
        if (i >= NCOL * 800) return;
        int n = i / 800, k = i % 800;
        BhA[i] = (_Float16)((n < GATES) ? mlpw1[(size_t)n * 1600 + k]
                                        : mlpw1[(size_t)(n - GATES) * 1600 + 800 + k]);
    }
}

// ---------------------------------------------------------------- MFMA f16 GEMM (as R6, verified)
__global__ __launch_bounds__(256) void gemm_f16(
    const _Float16* __restrict__ A, int Kp,
    const _Float16* __restrict__ B,
    const float* __restrict__ bias, float* __restrict__ C)
{
    const int tid  = threadIdx.x;
    const int w    = tid >> 6, lane = tid & 63;
    const int quad = lane >> 4, l16 = lane & 15;
    const int mb   = blockIdx.y * 32 + (w & 1) * 16;
    const int n0   = blockIdx.x * 64 + (w >> 1) * 32;
    const _Float16* Arow = A + (size_t)(mb + l16) * Kp + quad * 8;
    const _Float16* B0r  = B + (size_t)(n0 + l16) * Kp + quad * 8;
    const _Float16* B1r  = B0r + (size_t)16 * Kp;
    f32x4 acc0 = {0.f, 0.f, 0.f, 0.f}, acc1 = {0.f, 0.f, 0.f, 0.f};
#pragma unroll 4
    for (int k0 = 0; k0 < Kp; k0 += 32) {
        f16x8 a  = *(const f16x8*)(Arow + k0);
        f16x8 b0 = *(const f16x8*)(B0r + k0);
        f16x8 b1 = *(const f16x8*)(B1r + k0);
        acc0 = __builtin_amdgcn_mfma_f32_16x16x32_f16(a, b0, acc0, 0, 0, 0);
        acc1 = __builtin_amdgcn_mfma_f32_16x16x32_f16(a, b1, acc1, 0, 0, 0);
    }
    const int mr = mb + quad * 4;
    float bn0 = bias[n0 + l16], bn1 = bias[n0 + 16 + l16];
#pragma unroll
    for (int r = 0; r < 4; ++r) {
        C[(size_t)(mr + r) * NCOL + n0 + l16]      = acc0[r] + bn0;
        C[(size_t)(mr + r) * NCOL + n0 + 16 + l16] = acc1[r] + bn1;
    }
}

// ---------------------------------------------------------------- recurrence
// R12 = R11 + three changes targeting exchange latency (the measured floor):
// (1) XCD placement: grid=128, real WGs only at blockIdx%8<2 (dir=bid%8,
//     wg=bid>>3). Under the observed round-robin bid->XCD mapping, each
//     direction's 16 WGs share one XCD. Perf heuristic only.
// (2) Dual-path exchange: producer stores each packed dword to ex_slow
//     (agent-scope atomic -> MALL, correct under ANY placement) AND to
//     ex_fast (plain store -> write-through into the local L2). Consumer
//     polls both per iteration: inline-asm `global_load_dword ... sc0`
//     (L1-bypass, reads the XCD's shared L2 -> no L1-staleness spin) and
//     the agent load. Same-XCD: fast path clears in ~L2 RTT. Cross-XCD:
//     fast line stays stale-clean sentinel, slow path clears as in R11.
//     Different addresses -> no writeback clobber; region re-sentineled
//     between layers.
// (3) Pollers remapped to tid 64..271 (waves 1-4) so wave 0's act phase
//     no longer serializes 5 of the 16 line polls.
__global__ __launch_bounds__(1024, 4) void lstm_layer(
    const float* __restrict__ gates,   // SEQ x 3200 (x@W_ih^T + biases)
    const float* __restrict__ whh_f, const float* __restrict__ whh_b,
    const float* __restrict__ h0f, const float* __restrict__ h0b,
    const float* __restrict__ c0f, const float* __restrict__ c0b,
    unsigned* __restrict__ ex,         // [0,EXN): slow plane, [EXN,2*EXN): fast plane
    _Float16* __restrict__ ah)         // SEQ x 800 fp16 h (input to next GEMM)
{
    const int bid = blockIdx.x;
    if ((bid & 7) >= 2) return;        // dummy WG (placement trick)
    const int dir = bid & 7;           // 0 or 1
    const int wg  = bid >> 3;          // 0..15

    __shared__ unsigned h_pk[200];     // 400 halfs of h_prev
    __shared__ float part[16][28];
    unsigned short* hs = (unsigned short*)h_pk;
    const int tid = threadIdx.x;
    const int j0  = wg * RPW;
    const float* whh = dir ? whh_b : whh_f;
    const float* h0d = dir ? h0b : h0f;
    const float* c0d = dir ? c0b : c0f;

    const int w    = tid >> 6;         // wave 0..15
    const int lane = tid & 63;
    const int g    = w & 3;            // gate
    const int kq   = w >> 2;           // k-quarter (100 elems)
    const int half = lane & 1;         // k-split within quarter
    const int r    = lane >> 1;        // row within WG (active if r<25)
    const int jrow = j0 + (r < RPW ? r : RPW - 1);

    // one-time: 52 W_hh weights/thread, fp16-packed into 26 uints (spill-proof)
    unsigned wr[26];
    {
        const float2* wp = (const float2*)(whh + (size_t)(g * 400 + jrow) * 400 +
                                           kq * 100 + 48 * half);
#pragma unroll
        for (int i = 0; i < 26; ++i) {
            H2U cv; float2 f = wp[i];
            cv.hh = __floats2half2_rn(f.x, f.y);
            wr[i] = (half == 0 && i >= 24) ? 0u : cv.u;
        }
    }

    // pollers: tid 64..271 (waves 1-4), 16 producers x 13 dwords
    const bool is_poller = (tid >= 64 && tid < 272);
    const int pp = (tid - 64) / 13;    // producer block polled
    const int pd = (tid - 64) % 13;    // dword within block
    float c_prev = (tid < RPW) ? c0d[j0 + tid] : 0.f;

    for (int s = 0; s < 320; ++s) {
        const int row = dir ? (319 - s) : s;

        // gate prefetch (independent of h_prev, overlaps the poll)
        float gv0 = 0.f, gv1 = 0.f, gv2 = 0.f, gv3 = 0.f;
        if (tid < RPW) {
            const float* gx = gates + (size_t)row * NCOL + dir * GATES + j0 + tid;
            gv0 = gx[0]; gv1 = gx[400]; gv2 = gx[800]; gv3 = gx[1200];
        }

        if (s == 0) {
            if (tid < 100) {
                float4 f = ((const float4*)h0d)[tid];
                H2U a, b;
                a.hh = __floats2half2_rn(f.x, f.y);
                b.hh = __floats2half2_rn(f.z, f.w);
                ((uint2*)h_pk)[tid] = make_uint2(a.u, b.u);
            }
        } else if (is_poller && pp != wg) {
            const int rp = dir ? (row + 1) : (row - 1);
            const size_t off = (((size_t)dir * GDW + pp) * SEQ + rp) * 16 + pd;
            const unsigned* srcS = ex + off;
            const unsigned* srcF = ex + EXN + off;
            unsigned v;
            for (;;) {
                // issue slow (agent/MALL) load; memory clobber in the asm
                // keeps it before the fast load + waitcnt
                unsigned vs = __hip_atomic_load(srcS, __ATOMIC_RELAXED,
                                                __HIP_MEMORY_SCOPE_AGENT);
                unsigned vf;
                asm volatile("global_load_dword %0, %1, off sc0\n\t"
                             "s_waitcnt vmcnt(0)"
                             : "=v"(vf) : "v"(srcF) : "memory");
                if ((vf & 0xFFFFu) != 0xFFFFu &&
                    (pd == 12 || (vf >> 16) != 0xFFFFu)) { v = vf; break; }
                if ((vs & 0xFFFFu) != 0xFFFFu &&
                    (pd == 12 || (vs >> 16) != 0xFFFFu)) { v = vs; break; }
            }
            const int hb = pp * RPW + pd * 2;
            hs[hb] = (unsigned short)(v & 0xFFFFu);
            if (pd < 12) hs[hb + 1] = (unsigned short)(v >> 16);
        }
        // barrier 1: LDS-only drain (no vmcnt)
        asm volatile("s_waitcnt lgkmcnt(0)" ::: "memory");
        __builtin_amdgcn_s_barrier();

        // partial dot: 52 halves via 13 ds_read_b64 + 26 v_dot2_f32_f16
        {
            const uint2* hp2 = (const uint2*)h_pk + kq * 25 + 12 * half;
            float acc = 0.f;
#pragma unroll
            for (int i = 0; i < 13; ++i) {
                uint2 hv2 = hp2[i];
                H2U w0, w1, x0, x1;
                w0.u = wr[2 * i]; w1.u = wr[2 * i + 1];
                x0.u = hv2.x;     x1.u = hv2.y;
                acc = __builtin_amdgcn_fdot2(w0.h, x0.h, acc, false);
                acc = __builtin_amdgcn_fdot2(w1.h, x1.h, acc, false);
            }
            acc += __shfl_xor(acc, 1, 64);
            if (half == 0 && r < RPW) part[w][r] = acc;
        }
        // barrier 2: LDS-only drain
        asm volatile("s_waitcnt lgkmcnt(0)" ::: "memory");
        __builtin_amdgcn_s_barrier();

        // activation + exchange store (wave 0 only)
        float hv = 0.f;
        if (tid < RPW) {
            float gi = gv0 + ((part[0][tid] + part[4][tid]) + (part[8][tid]  + part[12][tid]));
            float gf = gv1 + ((part[1][tid] + part[5][tid]) + (part[9][tid]  + part[13][tid]));
            float gg = gv2 + ((part[2][tid] + part[6][tid]) + (part[10][tid] + part[14][tid]));
            float go = gv3 + ((part[3][tid] + part[7][tid]) + (part[11][tid] + part[15][tid]));
            float iv = 1.f / (1.f + __expf(-gi));
            float fv = 1.f / (1.f + __expf(-gf));
            float ov = 1.f / (1.f + __expf(-go));
            float tg = 1.f - 2.f / (1.f + __expf(2.f * gg));
            c_prev = fv * c_prev + iv * tg;
            float tc = 1.f - 2.f / (1.f + __expf(2.f * c_prev));
            hv = ov * tc;
        }
        if (w == 0) {
            int i0 = 2 * lane     < 63 ? 2 * lane     : 63;
            int i1 = 2 * lane + 1 < 63 ? 2 * lane + 1 : 63;
            float xlo = __shfl(hv, i0, 64);
            float xhi = __shfl(hv, i1, 64);
            if (lane < 13) {                 // one private 64B line per step, dual-plane
                H2U pk;
                pk.hh = __floats2half2_rn(xlo, (2 * lane + 1 < RPW) ? xhi : 0.f);
                const size_t off = (((size_t)dir * GDW + wg) * SEQ + row) * 16 + lane;
                __hip_atomic_store(ex + off, pk.u,
                                   __ATOMIC_RELAXED, __HIP_MEMORY_SCOPE_AGENT);
                ex[EXN + off] = pk.u;        // plain store -> local L2 (fast plane)
            }
            if (tid < RPW) {                 // fp16 h for next GEMM + own-row LDS
                ah[(size_t)row * 800 + dir * 400 + j0 + tid] = (_Float16)hv;
                H2U o; o.hh = __floats2half2_rn(hv, 0.f);
                hs[RPW * wg + tid] = (unsigned short)(o.u & 0xFFFFu);
            }
        }
        // hazards: identical to R11 (poll/act writes vs dot reads separated by
        // the two lgkmcnt-drained barriers; disjoint LDS ranges). safe.
    }
}

// ---------------------------------------------------------------- fused scorer (+ border rows)
__global__ __launch_bounds__(256) void scores_kernel(
    const float* __restrict__ ab, const float* __restrict__ w2,
    const float* __restrict__ b2, float* __restrict__ out)
{
    if (blockIdx.y == 20) {              // border: row 0 / col 0
        int i = blockIdx.x * 256 + threadIdx.y * 16 + threadIdx.x;
        if (blockIdx.x < 2 && i < 321) {
            out[i]               = (i == 0) ? 1.f : 0.f;
            out[(size_t)i * 321] = (i == 0) ? 1.f : 0.f;
        }
        return;
    }
    __shared__ float a_s[16 * 132];
    __shared__ float b_s[16 * 132];
    __shared__ float w_s[128];
    const int tx = threadIdx.x, ty = threadIdx.y;
    const int tid = ty * 16 + tx;
    const int n0 = blockIdx.y * 16, d0 = blockIdx.x * 16;
    float acc = 0.f;
    for (int kc = 0; kc < 1600; kc += 128) {
        for (int i = tid; i < 16 * 128; i += 256) {
            int r = i >> 7, c = i & 127;
            a_s[r * 132 + c] = ab[(size_t)(n0 + r) * NCOL + kc + c];
            b_s[r * 132 + c] = ab[(size_t)(d0 + r) * NCOL + 1600 + kc + c];
        }
        if (tid < 128) w_s[tid] = w2[kc + tid];
        __syncthreads();
#pragma unroll
        for (int k = 0; k < 128; k += 4) {
            float4 av = *(const float4*)&a_s[ty * 132 + k];
            float4 bv = *(const float4*)&b_s[tx * 132 + k];
            float4 wv = *(const float4*)&w_s[k];
            acc += fmaxf(av.x + bv.x, 0.f) * wv.x;
            acc += fmaxf(av.y + bv.y, 0.f) * wv.y;
            acc += fmaxf(av.z + bv.z, 0.f) * wv.z;
            acc += fmaxf(av.w + bv.w, 0.f) * wv.w;
        }
        __syncthreads();
    }
    int n = n0 + ty, d = d0 + tx;
    out[(size_t)(n + 1) * 321 + (d + 1)] = (n == d) ? 0.f : (acc + b2[0]);
}

// ---------------------------------------------------------------- launcher
extern "C" void kernel_launch(void* const* d_in, const int* in_sizes, int n_in,
                              void* d_out, int out_size, void* d_ws, size_t ws_size,
                              hipStream_t stream)
{
    const int*   words    = (const int*)d_in[0];
    const int*   tags     = (const int*)d_in[1];
    const float* wemb     = (const float*)d_in[3];
    const float* temb     = (const float*)d_in[4];
    const float* h0       = (const float*)d_in[5];
    const float* c0       = (const float*)d_in[6];
    const float* w_ih_l0  = (const float*)d_in[7];
    const float* w_hh_l0  = (const float*)d_in[8];
    const float* b_ih_l0  = (const float*)d_in[9];
    const float* b_hh_l0  = (const float*)d_in[10];
    const float* w_ih_l0r = (const float*)d_in[11];
    const float* w_hh_l0r = (const float*)d_in[12];
    const float* b_ih_l0r = (const float*)d_in[13];
    const float* b_hh_l0r = (const float*)d_in[14];
    const float* w_ih_l1  = (const float*)d_in[15];
    const float* w_hh_l1  = (const float*)d_in[16];
    const float* b_ih_l1  = (const float*)d_in[17];
    const float* b_hh_l1  = (const float*)d_in[18];
    const float* w_ih_l1r = (const float*)d_in[19];
    const float* w_hh_l1r = (const float*)d_in[20];
    const float* b_ih_l1r = (const float*)d_in[21];
    const float* b_hh_l1r = (const float*)d_in[22];
    const float* mlp_w1   = (const float*)d_in[23];
    const float* mlp_b1   = (const float*)d_in[24];
    const float* mlp_w2   = (const float*)d_in[25];
    const float* mlp_b2   = (const float*)d_in[26];
    float* out = (float*)d_out;

    float* ws      = (float*)d_ws;
    float*    gates  = ws;                              // 320*3200 = 1,024,000 f32
    float*    biasL0 = ws + 1024000;
    float*    biasL1 = ws + 1027200;
    float*    biasAB = ws + 1030400;
    unsigned* ex     = (unsigned*)(ws + 1033600);       // slow+fast planes, 327,680 u32
    _Float16* Ah0    = (_Float16*)(ws + 1361280);       // 320*416 halves
    _Float16* Ah1    = (_Float16*)(ws + 1427840);       // 320*800 halves
    _Float16* Ah2    = (_Float16*)(ws + 1555840);       // 320*800 halves
    _Float16* BhA    = (_Float16*)(ws + 1683840);       // up to 3200*800 halves
    _Float16* BhB    = (_Float16*)(ws + 2963840);       // 3200*800 halves

    // sentinel-fill both exchange planes (data doubles as ready flag)
    hipMemsetAsync(ex, 0xFF, 327680u * 4, stream);

    prep_kernel<<<5733, 256, 0, stream>>>(
        words, tags, wemb, temb, Ah0,
        b_ih_l0, b_hh_l0, b_ih_l0r, b_hh_l0r,
        b_ih_l1, b_hh_l1, b_ih_l1r, b_hh_l1r,
        mlp_b1, biasL0, biasL1, biasAB, w_ih_l0, w_ih_l0r, BhA);

    gemm_f16<<<dim3(50, 10), 256, 0, stream>>>(Ah0, 416, BhA, biasL0, gates);
    cvt2_kernel<<<20000, 256, 0, stream>>>(w_ih_l1, w_ih_l1r, BhB, mlp_w1, BhA);
    lstm_layer<<<128, 1024, 0, stream>>>(gates, w_hh_l0, w_hh_l0r,
                                         h0, h0 + 400, c0, c0 + 400, ex, Ah1);
    // re-sentinel both planes for layer 1 (stream-ordered after lstm L0)
    hipMemsetAsync(ex, 0xFF, 327680u * 4, stream);
    gemm_f16<<<dim3(50, 10), 256, 0, stream>>>(Ah1, 800, BhB, biasL1, gates);
    lstm_layer<<<128, 1024, 0, stream>>>(gates, w_hh_l1, w_hh_l1r,
                                         h0 + 800, h0 + 1200, c0 + 800, c0 + 1200,
                                         ex, Ah2);
    gemm_f16<<<dim3(50, 10), 256, 0, stream>>>(Ah2, 800, BhA, biasAB, gates);

    scores_kernel<<<dim3(20, 21), dim3(16, 16), 0, stream>>>(gates, mlp_w2, mlp_b2, out);
}